// Round 5
// baseline (5004.850 us; speedup 1.0000x reference)
//
#include <hip/hip_runtime.h>
#include <cstdint>
#include <cstddef>

// HiPPO x_{k+1} = Ab x_k + b u_k, f[k]=x_{k+1}, L=65536, N=512.
// Chunked scan (C=16, G=4096): one big GEMM F(4096x8192)=Xcat(4096x544)@Wcat,
// chunk states via Blelloch sweep with on-device matrix powers.
// Numerics: split-f16 (Ootomo, scale 2048), fp32 accumulate -> ~22-bit mantissa.
// R5: ALL serial stages (chain, kbuild, wcat, leaf, up/down sweep, xtail) fused
// into ONE persistent kernel with a software grid barrier -> 5 dispatches total.
// (R4 showed 703 of 955 us was ~41 dependent small launches at ~17 us each.)

typedef _Float16 half_t;
typedef _Float16 f16x8 __attribute__((ext_vector_type(8)));
typedef float f32x4 __attribute__((ext_vector_type(4)));

static constexpr int KPAD = 544;               // 512 + 16 u-taps + 16 pad
static constexpr size_t MSZ = (size_t)512 * 512;
static constexpr float INV2048 = 1.f / 2048.f;
static constexpr int NBLK = 512;               // persistent grid (2 blocks/CU)

__device__ inline void split1(float v, half_t& h, half_t& l) {
  h = (half_t)v;
  l = (half_t)((v - (float)h) * 2048.f);
}

// ---------------- software grid barrier (co-resident persistent grid) -------
__device__ inline void gsync(unsigned* bar, unsigned target) {
  __syncthreads();
  if (threadIdx.x == 0) {
    __threadfence();   // make this block's writes visible device-wide
    __hip_atomic_fetch_add(bar, 1u, __ATOMIC_RELEASE, __HIP_MEMORY_SCOPE_AGENT);
    while (__hip_atomic_load(bar, __ATOMIC_ACQUIRE, __HIP_MEMORY_SCOPE_AGENT) < target)
      __builtin_amdgcn_s_sleep(1);
    __threadfence();   // invalidate stale lines before next phase's reads
  }
  __syncthreads();
}

// ---------------- small pre-launch kernels ----------------

__global__ void zero_kernel(float4* __restrict__ p, int n4) {
  int i = blockIdx.x * 256 + threadIdx.x;
  if (i < n4) p[i] = make_float4(0.f, 0.f, 0.f, 0.f);
}

__global__ void copy_ab_kernel(const float* __restrict__ Ab, float* __restrict__ V0) {
  int idx = blockIdx.x * 256 + threadIdx.x;    // 262144
  V0[idx] = Ab[idx];
}

__global__ void cast_x0_kernel(const float* __restrict__ x0, half_t* __restrict__ xh,
                               unsigned* __restrict__ bar) {
  xh[threadIdx.x] = (half_t)x0[threadIdx.x];
  if (threadIdx.x == 0) *bar = 0u;
}

// ---------------- device helpers for the persistent kernel ----------------

// chain product slice: C(512x512 fp32) += A @ B (fp32 in, split-f16 3-mfma),
// vb in [0,256): sl=vb>>6 (K-slice of 4 kt), mt=(vb>>3)&7, nt=vb&7
__device__ void chain_vb(const float* A, const float* B, float* C, int vb,
                         half_t* Ash, half_t* Asl, half_t* Bsh, half_t* Bsl) {
  int sl = vb >> 6, mt = (vb >> 3) & 7, nt = vb & 7;
  int m0 = mt * 64, n0 = nt * 64;
  int tid = threadIdx.x, wave = tid >> 6, lane = tid & 63;
  int wm = (wave & 1) * 32, wn = (wave >> 1) * 32;
  f32x4 acc[2][2], accc[2][2];
  for (int i = 0; i < 2; ++i)
    for (int j = 0; j < 2; ++j) {
      acc[i][j] = (f32x4){0.f, 0.f, 0.f, 0.f};
      accc[i][j] = (f32x4){0.f, 0.f, 0.f, 0.f};
    }
  int rb = tid >> 6, mm = tid & 15, kseg = (tid >> 4) & 3;
  for (int kt = sl * 4; kt < sl * 4 + 4; ++kt) {
    int k0 = kt * 32;
    {  // A: row-major fp32, fragment gather -> linear LDS
      const float* ap = A + (size_t)(m0 + rb * 16 + mm) * 512 + k0 + kseg * 8;
      f16x8 hv, lv;
#pragma unroll
      for (int j = 0; j < 8; ++j) { half_t h, l; split1(ap[j], h, l); hv[j] = h; lv[j] = l; }
      *(f16x8*)(Ash + tid * 8) = hv;
      *(f16x8*)(Asl + tid * 8) = lv;
    }
    {  // B: column gather (transpose), fragment order
      f16x8 hv, lv;
#pragma unroll
      for (int j = 0; j < 8; ++j) {
        float v = B[(size_t)(k0 + kseg * 8 + j) * 512 + n0 + rb * 16 + mm];
        half_t h, l; split1(v, h, l); hv[j] = h; lv[j] = l;
      }
      *(f16x8*)(Bsh + tid * 8) = hv;
      *(f16x8*)(Bsl + tid * 8) = lv;
    }
    __syncthreads();
    f16x8 afh[2], afl[2], bfh[2], bfl[2];
#pragma unroll
    for (int i = 0; i < 2; ++i) {
      int ra = (wm >> 4) + i, rbn = (wn >> 4) + i;
      afh[i] = *(const f16x8*)(Ash + ra * 512 + lane * 8);
      afl[i] = *(const f16x8*)(Asl + ra * 512 + lane * 8);
      bfh[i] = *(const f16x8*)(Bsh + rbn * 512 + lane * 8);
      bfl[i] = *(const f16x8*)(Bsl + rbn * 512 + lane * 8);
    }
#pragma unroll
    for (int i = 0; i < 2; ++i)
#pragma unroll
      for (int j = 0; j < 2; ++j) {
        acc[i][j] = __builtin_amdgcn_mfma_f32_16x16x32_f16(afh[i], bfh[j], acc[i][j], 0, 0, 0);
        accc[i][j] = __builtin_amdgcn_mfma_f32_16x16x32_f16(afh[i], bfl[j], accc[i][j], 0, 0, 0);
        accc[i][j] = __builtin_amdgcn_mfma_f32_16x16x32_f16(afl[i], bfh[j], accc[i][j], 0, 0, 0);
      }
    __syncthreads();
  }
  int ml = lane & 15, quad = lane >> 4;
  for (int i = 0; i < 2; ++i)
    for (int j = 0; j < 2; ++j)
      for (int rr = 0; rr < 4; ++rr) {
        int gm = m0 + wm + i * 16 + quad * 4 + rr;
        int gn = n0 + wn + j * 16 + ml;
        atomicAdd(&C[(size_t)gm * 512 + gn], acc[i][j][rr] + accc[i][j][rr] * INV2048);
      }
}

// sweep slice: C(Mx512) = A(Mx512 f16) @ S^T + D; S fp32 row-major (split).
// vb = mt*8+nt. Fused even-row copy (down-sweep).
__device__ void sweep_vb(const half_t* A, long ldA, const float* BT,
                         const half_t* D, long ldD, half_t* Ch, half_t* Cl,
                         long ldC, int rScale, int rOff, int doCopy, int M, int vb,
                         half_t* Ash, half_t* Bsh, half_t* Bsl) {
  int mt = vb >> 3, nt = vb & 7;
  int m0 = mt * 64, n0 = nt * 64;
  int tid = threadIdx.x, wave = tid >> 6, lane = tid & 63;
  int wm = (wave & 1) * 32, wn = (wave >> 1) * 32;
  f32x4 acc[2][2], accc[2][2];
  for (int i = 0; i < 2; ++i)
    for (int j = 0; j < 2; ++j) {
      acc[i][j] = (f32x4){0.f, 0.f, 0.f, 0.f};
      accc[i][j] = (f32x4){0.f, 0.f, 0.f, 0.f};
    }
  int rb = tid >> 6, mm = tid & 15, kseg = (tid >> 4) & 3;
  for (int kt = 0; kt < 16; ++kt) {
    int k0 = kt * 32;
    int arow = m0 + rb * 16 + mm;
    f16x8 av = (f16x8){0, 0, 0, 0, 0, 0, 0, 0};
    if (arow < M) av = *(const f16x8*)(A + (size_t)arow * ldA + k0 + kseg * 8);
    *(f16x8*)(Ash + tid * 8) = av;
    if (doCopy && k0 >= n0 && k0 < n0 + 64 && arow < M) {
      size_t co = (size_t)(2 * arow) * ldC + k0 + kseg * 8;
      *(f16x8*)(Ch + co) = av;
      if (Cl) *(f16x8*)(Cl + co) = (f16x8){0, 0, 0, 0, 0, 0, 0, 0};
    }
    {  // S row gather (fp32) -> split fragment
      const float* bp = BT + (size_t)(n0 + rb * 16 + mm) * 512 + k0 + kseg * 8;
      f16x8 hv, lv;
#pragma unroll
      for (int j = 0; j < 8; ++j) { half_t h, l; split1(bp[j], h, l); hv[j] = h; lv[j] = l; }
      *(f16x8*)(Bsh + tid * 8) = hv;
      *(f16x8*)(Bsl + tid * 8) = lv;
    }
    __syncthreads();
    f16x8 af[2], bfh[2], bfl[2];
#pragma unroll
    for (int i = 0; i < 2; ++i) {
      af[i] = *(const f16x8*)(Ash + ((wm >> 4) + i) * 512 + lane * 8);
      bfh[i] = *(const f16x8*)(Bsh + ((wn >> 4) + i) * 512 + lane * 8);
      bfl[i] = *(const f16x8*)(Bsl + ((wn >> 4) + i) * 512 + lane * 8);
    }
#pragma unroll
    for (int i = 0; i < 2; ++i)
#pragma unroll
      for (int j = 0; j < 2; ++j) {
        acc[i][j] = __builtin_amdgcn_mfma_f32_16x16x32_f16(af[i], bfh[j], acc[i][j], 0, 0, 0);
        accc[i][j] = __builtin_amdgcn_mfma_f32_16x16x32_f16(af[i], bfl[j], accc[i][j], 0, 0, 0);
      }
    __syncthreads();
  }
  int ml = lane & 15, quad = lane >> 4;
  for (int i = 0; i < 2; ++i)
    for (int j = 0; j < 2; ++j)
      for (int rr = 0; rr < 4; ++rr) {
        int gm = m0 + wm + i * 16 + quad * 4 + rr;
        int gn = n0 + wn + j * 16 + ml;
        if (gm >= M) continue;
        float v = acc[i][j][rr] + accc[i][j][rr] * INV2048;
        if (D) v += (float)D[(size_t)gm * ldD + gn];
        size_t co = ((size_t)gm * rScale + rOff) * ldC + gn;
        if (Cl) { half_t h, l; split1(v, h, l); Ch[co] = h; Cl[co] = l; }
        else Ch[co] = (half_t)v;
      }
}

__device__ void dev_kbuild(const float* V, const float* b, float* K) {
  int wave = threadIdx.x >> 6, lane = threadIdx.x & 63;
  for (int gw = blockIdx.x * 4 + wave; gw < 8192; gw += NBLK * 4) {
    int t = gw >> 9, n = gw & 511;
    if (t == 0) { if (lane == 0) K[n] = b[n]; continue; }
    const float* row = V + (size_t)(t - 1) * MSZ + (size_t)n * 512;
    float acc = 0.f;
#pragma unroll
    for (int m = 0; m < 512; m += 64) acc += row[m + lane] * b[m + lane];
#pragma unroll
    for (int s = 32; s; s >>= 1) acc += __shfl_down(acc, s, 64);
    if (lane == 0) K[t * 512 + n] = acc;
  }
}

__device__ void dev_wcat(const float* V, const float* K, half_t* Wh, half_t* Wl) {
  const size_t total = (size_t)8192 * KPAD;
  for (size_t idx = (size_t)blockIdx.x * 256 + threadIdx.x; idx < total;
       idx += (size_t)NBLK * 256) {
    int row = (int)(idx / KPAD), k = (int)(idx % KPAD);
    int i = row >> 9, n = row & 511;
    float v = 0.f;
    if (k < 512) v = V[(size_t)i * MSZ + (size_t)n * 512 + k];
    else if (k < 528) { int j = k - 512; if (j <= i) v = K[(i - j) * 512 + n]; }
    half_t h, l; split1(v, h, l);
    Wh[idx] = h; Wl[idx] = l;
  }
}

__device__ void dev_leaf(const float* u, const float* K, half_t* Z) {
  for (int idx = blockIdx.x * 256 + threadIdx.x; idx < 4096 * 512; idx += NBLK * 256) {
    int c = idx >> 9, n = idx & 511;
    float acc = 0.f;
#pragma unroll
    for (int j = 0; j < 16; ++j) acc += K[(15 - j) * 512 + n] * u[c * 16 + j];
    Z[idx] = (half_t)acc;
  }
}

__device__ void dev_xtail(const float* u, half_t* Xh, half_t* Xl) {
  for (int idx = blockIdx.x * 256 + threadIdx.x; idx < 4096 * 32; idx += NBLK * 256) {
    int c = idx >> 5, j = idx & 31;
    float v = (j < 16) ? u[c * 16 + j] : 0.f;
    size_t o = (size_t)c * KPAD + 512 + j;
    half_t h, l; split1(v, h, l);
    Xh[o] = h; Xl[o] = l;
  }
}

// ---------------- the persistent serial-pipeline kernel ----------------
// Phases: V-chain(4) -> squarings(11, kbuild folded in last) -> wcat(1) ->
// leaf(1) -> up-sweep(11) -> down-sweep(12, xtail folded in l=0). 40 gsyncs.
// NOTE: pointers intentionally NOT __restrict__ (Zh/Xph alias Vp, Xc* alias Sp).
__global__ __launch_bounds__(256, 2)
void coop_kernel(float* Vp, float* Sp, float* Kb, half_t* Wh, half_t* Wl,
                 half_t* Zh, half_t* Xph, half_t* Xch, half_t* Xcl, half_t* x0h,
                 const float* u, const float* Bb, unsigned* bar) {
  __shared__ __align__(16) half_t sA[2048], sB[2048], sC[2048], sD[2048];
  unsigned ph = 0;
  auto sync = [&]() { ++ph; gsync(bar, ph * NBLK); };
  auto zoff = [](int l) -> size_t { return (size_t)512 * (8192 - (8192 >> l)); };
  auto xoff = [](int l) -> size_t { return (size_t)512 * (4096 - (8192 >> l)); };

  // V-chain by doubling: V_{t+s} = V_t @ V_s, t=1..s (batched), s=1,2,4,8
  for (int s = 1; s <= 8; s <<= 1) {
    int NV = 256 * s;
    for (int v = blockIdx.x; v < NV; v += NBLK) {
      int bb = v >> 8, vb = v & 255;
      chain_vb(Vp + (size_t)bb * MSZ, Vp + (size_t)(s - 1) * MSZ,
               Vp + (size_t)(s + bb) * MSZ, vb, sA, sB, sC, sD);
    }
    sync();
  }
  // Squarings: S_1 = (Ab^16)^2, S_l = S_{l-1}^2   (kbuild folded into l=11)
  for (int l = 1; l <= 11; ++l) {
    const float* Aop = (l == 1) ? Vp + 15 * MSZ : Sp + (size_t)(l - 2) * MSZ;
    float* Cop = Sp + (size_t)(l - 1) * MSZ;
    for (int v = blockIdx.x; v < 256; v += NBLK)
      chain_vb(Aop, Aop, Cop, v, sA, sB, sC, sD);
    if (l == 11) dev_kbuild(Vp, Bb, Kb);
    sync();
  }
  dev_wcat(Vp, Kb, Wh, Wl);
  sync();
  // leaf overwrites V[0..14] region (Zh overlay) — V fully consumed by wcat
  dev_leaf(u, Kb, Zh);
  sync();
  // Up-sweep: Z_{l+1}[j] = S_l Z_l[2j] + Z_l[2j+1]
  for (int l = 0; l <= 10; ++l) {
    int M = 1 << (11 - l);
    const float* S = (l == 0) ? Vp + 15 * MSZ : Sp + (size_t)(l - 1) * MSZ;
    int NV = ((M + 63) / 64) * 8;
    for (int v = blockIdx.x; v < NV; v += NBLK)
      sweep_vb(Zh + zoff(l), 1024L, S, Zh + zoff(l) + 512, 1024L,
               Zh + zoff(l + 1), (half_t*)0, 512L, 1, 0, 0, M, v, sA, sB, sC);
    sync();
  }
  // Down-sweep: X_l[2j+1] = S_l X_{l+1}[j] + Z_l[2j]; X_l[2j] = X_{l+1}[j]
  for (int l = 11; l >= 0; --l) {
    int M = 1 << (11 - l);
    const float* S = (l == 0) ? Vp + 15 * MSZ : Sp + (size_t)(l - 1) * MSZ;
    const half_t* Xup = (l == 11) ? x0h : Xph + xoff(l + 1);
    half_t* Ch = (l == 0) ? Xch : Xph + xoff(l);
    half_t* Cl = (l == 0) ? Xcl : (half_t*)0;
    long ldC = (l == 0) ? (long)KPAD : 512L;
    int NV = ((M + 63) / 64) * 8;
    for (int v = blockIdx.x; v < NV; v += NBLK)
      sweep_vb(Xup, 512L, S, Zh + zoff(l), 1024L, Ch, Cl, ldC, 2, 1, 1, M, v,
               sA, sB, sC);
    if (l == 0) dev_xtail(u, Xch, Xcl);   // Sp dead after l=1 -> overlay live
    if (l > 0) sync();
  }
}

// -------- main GEMM: 4096 x 8192 x 544, 128x128 tile, split operands --------
__device__ inline void load_lds16(const half_t* g, half_t* l) {
  __builtin_amdgcn_global_load_lds(
      (const __attribute__((address_space(1))) uint32_t*)g,
      (__attribute__((address_space(3))) uint32_t*)l, 16, 0, 0);
}

__global__ __launch_bounds__(256)
void gemm_main(const half_t* __restrict__ Ah, const half_t* __restrict__ Al,
               const half_t* __restrict__ Bh, const half_t* __restrict__ Bl,
               float* __restrict__ C) {
  __shared__ __align__(16) half_t Ash[128 * 32];
  __shared__ __align__(16) half_t Asl[128 * 32];
  __shared__ __align__(16) half_t Bsh[128 * 32];
  __shared__ __align__(16) half_t Bsl[128 * 32];
  int n0 = blockIdx.x * 128, m0 = blockIdx.y * 128;
  int tid = threadIdx.x, wave = tid >> 6, lane = tid & 63;
  int wm = (wave & 1) * 64, wn = (wave >> 1) * 64;
  int mm = lane & 15, kseg = lane >> 4;
  f32x4 acc[4][4], accc[4][4];
  for (int i = 0; i < 4; ++i)
    for (int j = 0; j < 4; ++j) {
      acc[i][j] = (f32x4){0.f, 0.f, 0.f, 0.f};
      accc[i][j] = (f32x4){0.f, 0.f, 0.f, 0.f};
    }
  for (int kt = 0; kt < 17; ++kt) {
    int k0 = kt * 32;
#pragma unroll
    for (int q = 0; q < 2; ++q) {
      int c = wave + 4 * q;
      size_t ga = (size_t)(m0 + c * 16 + mm) * KPAD + k0 + kseg * 8;
      size_t gb = (size_t)(n0 + c * 16 + mm) * KPAD + k0 + kseg * 8;
      size_t lo = (size_t)c * 512;
      load_lds16(Ah + ga, Ash + lo);
      load_lds16(Al + ga, Asl + lo);
      load_lds16(Bh + gb, Bsh + lo);
      load_lds16(Bl + gb, Bsl + lo);
    }
    __syncthreads();
    f16x8 afh[4], afl[4], bfh[4], bfl[4];
#pragma unroll
    for (int i = 0; i < 4; ++i) {
      int ra = (wm >> 4) + i, rbn = (wn >> 4) + i;
      afh[i] = *(const f16x8*)(Ash + ra * 512 + lane * 8);
      afl[i] = *(const f16x8*)(Asl + ra * 512 + lane * 8);
      bfh[i] = *(const f16x8*)(Bsh + rbn * 512 + lane * 8);
      bfl[i] = *(const f16x8*)(Bsl + rbn * 512 + lane * 8);
    }
#pragma unroll
    for (int i = 0; i < 4; ++i)
#pragma unroll
      for (int j = 0; j < 4; ++j) {
        acc[i][j] = __builtin_amdgcn_mfma_f32_16x16x32_f16(afh[i], bfh[j], acc[i][j], 0, 0, 0);
        accc[i][j] = __builtin_amdgcn_mfma_f32_16x16x32_f16(afh[i], bfl[j], accc[i][j], 0, 0, 0);
        accc[i][j] = __builtin_amdgcn_mfma_f32_16x16x32_f16(afl[i], bfh[j], accc[i][j], 0, 0, 0);
      }
    __syncthreads();
  }
  int ml = lane & 15, quad = lane >> 4;
  for (int i = 0; i < 4; ++i)
    for (int j = 0; j < 4; ++j) {
      int gm = m0 + wm + i * 16 + quad * 4;
      int gn = n0 + wn + j * 16 + ml;
      float* o = C + (size_t)gm * 8192 + gn;
      for (int rr = 0; rr < 4; ++rr)
        o[(size_t)rr * 8192] = acc[i][j][rr] + accc[i][j][rr] * INV2048;
    }
}

// ---------------- host orchestration ----------------

extern "C" void kernel_launch(void* const* d_in, const int* in_sizes, int n_in,
                              void* d_out, int out_size, void* d_ws, size_t ws_size,
                              hipStream_t stream) {
  (void)in_sizes; (void)n_in; (void)out_size; (void)ws_size;
  const float* u  = (const float*)d_in[0];   // 65536
  const float* Ab = (const float*)d_in[1];   // 512x512
  const float* Bb = (const float*)d_in[2];   // 512
  const float* x0 = (const float*)d_in[3];   // 512
  float* out = (float*)d_out;                // 65536x512 fp32

  char* base = (char*)d_ws;
  size_t off = 0;
  auto carve = [&](size_t bytes) -> char* {
    char* p = base + off;
    off = (off + bytes + 255) & ~(size_t)255;
    return p;
  };
  float*  Vp  = (float*)carve(16 * MSZ * 4);             // Ab^1..Ab^16 fp32
  float*  Sp  = (float*)carve(11 * MSZ * 4);             // Ab^{16*2^l}, l=1..11
  float*  Kb  = (float*)carve((size_t)16 * 512 * 4);
  half_t* Wh  = (half_t*)carve((size_t)8192 * KPAD * 2);
  half_t* Wl  = (half_t*)carve((size_t)8192 * KPAD * 2);
  half_t* x0h = (half_t*)carve(512 * 2);
  unsigned* bar = (unsigned*)carve(256);
  // Overlays (phase-ordered dead-region reuse, verified in r3/r4):
  size_t zend = (size_t)512 * (8192 - 2);                // zoff(12)
  half_t* Zh  = (half_t*)Vp;                             // over V[0..~8]
  half_t* Xph = (half_t*)((char*)Vp + ((zend * 2 + 255) & ~(size_t)255));
  half_t* Xch = (half_t*)Sp;                             // over Sp (dead)
  half_t* Xcl = (half_t*)((char*)Sp + (((size_t)4096 * KPAD * 2 + 255) & ~(size_t)255));

  // Zero chain outputs (Vp slots 1..15 + Sp, contiguous 26*MSZ) for atomicAdd
  {
    int n4 = (int)(26 * MSZ / 4);
    hipLaunchKernelGGL(zero_kernel, dim3((n4 + 255) / 256), dim3(256), 0, stream,
                       (float4*)(Vp + MSZ), n4);
  }
  hipLaunchKernelGGL(copy_ab_kernel, dim3(1024), dim3(256), 0, stream, Ab, Vp);
  hipLaunchKernelGGL(cast_x0_kernel, dim3(1), dim3(512), 0, stream, x0, x0h, bar);

  // ONE persistent kernel for the whole serial pipeline (40 device barriers)
  hipLaunchKernelGGL(coop_kernel, dim3(NBLK), dim3(256), 0, stream,
                     Vp, Sp, Kb, Wh, Wl, Zh, Xph, Xch, Xcl, x0h, u, Bb, bar);

  // Main GEMM: all 65536x512 outputs, fp32 store.
  hipLaunchKernelGGL(gemm_main, dim3(64, 32), dim3(256), 0, stream, Xch, Xcl, Wh, Wl, out);
}